// Round 1
// baseline (566.550 us; speedup 1.0000x reference)
//
#include <hip/hip_runtime.h>
#include <hip/hip_fp16.h>

// Problem constants (from reference)
#define N_SAMPLES 524288
#define N_FEATURES 64
#define N_GATES 64
#define N_OUTPUTS 8
#define BASE_COLS 66          // N_FEATURES + 2 (zero col, one col)
#define MAX_CONN 130          // BASE + N_GATES

#define NWORDS (N_SAMPLES / 2)   // 262144 half2 words per XT row (2 samples/word)
#define XT_ROWS 66               // 64 features + const0 row + const1 row
#define CH 8                     // gates per schedule chunk
#define MAXSLOTS 512             // worst case: 64 levels x 8 padded slots

typedef float v2f __attribute__((ext_vector_type(2)));

// ---------------------------------------------------------------------------
// top-2 insert, tie-break lower index (matches jax.lax.top_k stable order)
// ---------------------------------------------------------------------------
__device__ __forceinline__ void top2_ins(float x, int j, float& v1, int& i1, float& v2, int& i2) {
    bool gt1 = (x > v1) || (x == v1 && j < i1);
    bool gt2 = (x > v2) || (x == v2 && j < i2);
    if (gt1) { v2 = v1; i2 = i1; v1 = x; i1 = j; }
    else if (gt2) { v2 = x; i2 = j; }
}

// ---------------------------------------------------------------------------
// Kernel 1: plan. Computes top-2 per gate, then a level schedule:
// gates grouped into chunks of 8 with no intra-chunk dependencies
// (chunks never span dataflow levels; levels padded with no-op slots).
// Emits: slots[s] = {encA, encB, ldsWriteRow, origGate(-1 pad)},
//        owS[s][8] = output weights in schedule order (0 for pads).
// Encoding: e < 64 -> XT feature row e; 64/65 -> const rows; e >= 66 -> LDS gate row e-66.
// ---------------------------------------------------------------------------
__global__ __launch_bounds__(64) void plan_kernel(
    const float* __restrict__ gw,
    const float* __restrict__ ow,
    int4*  __restrict__ slots,
    float* __restrict__ owS,
    int*   __restrict__ nch)
{
    __shared__ int2 t2[N_GATES];
    __shared__ int  lvl[N_GATES];
    __shared__ int  ord[MAXSLOTS];
    __shared__ int  ns_sh;

    const int l = threadIdx.x;   // lane 0..63

    // ---- phase 1: top-2 of masked weights for each gate (softmax is monotone, T=1)
    for (int i = 0; i < N_GATES; ++i) {
        const float* w = gw + i * MAX_CONN;
        const int avail = BASE_COLS + i;
        float v1 = -1e30f, v2 = -1e30f;
        int   i1 = 0x7fffffff, i2 = 0x7fffffff;
        #pragma unroll
        for (int s = 0; s < 3; ++s) {
            int j = l + 64 * s;
            if (j < avail) top2_ins(w[j], j, v1, i1, v2, i2);
        }
        #pragma unroll
        for (int d = 1; d < 64; d <<= 1) {
            float ov1 = __shfl_xor(v1, d);
            int   oi1 = __shfl_xor(i1, d);
            float ov2 = __shfl_xor(v2, d);
            int   oi2 = __shfl_xor(i2, d);
            top2_ins(ov1, oi1, v1, i1, v2, i2);
            top2_ins(ov2, oi2, v1, i1, v2, i2);
        }
        if (l == 0) t2[i] = make_int2(i1, i2);
    }
    __syncthreads();

    // ---- phase 2: dataflow levels + chunked schedule (lane 0 serial, trivial size)
    if (l == 0) {
        int maxL = 0;
        for (int i = 0; i < N_GATES; ++i) {
            int2 p = t2[i];
            int L = 0;
            if (p.x >= BASE_COLS) L = lvl[p.x - BASE_COLS] + 1;
            if (p.y >= BASE_COLS) { int Lb = lvl[p.y - BASE_COLS] + 1; if (Lb > L) L = Lb; }
            lvl[i] = L;
            if (L > maxL) maxL = L;
        }
        int ns = 0;
        for (int L = 0; L <= maxL; ++L) {
            for (int i = 0; i < N_GATES; ++i)
                if (lvl[i] == L) ord[ns++] = i;
            while (ns & (CH - 1)) ord[ns++] = -1;   // pad level to chunk multiple
        }
        ns_sh = ns;
        *nch = ns / CH;
    }
    __syncthreads();

    // ---- phase 3: emit slot records + schedule-ordered weights (all lanes)
    const int ns = ns_sh;
    for (int s = l; s < ns; s += 64) {
        int g = ord[s];
        if (g >= 0) {
            int2 p = t2[g];
            slots[s] = make_int4(p.x, p.y, g, g);
            #pragma unroll
            for (int o = 0; o < N_OUTPUTS; ++o) owS[s * N_OUTPUTS + o] = ow[g * N_OUTPUTS + o];
        } else {
            // pad: reads const-0 row, writes dummy LDS row 64, zero weights
            slots[s] = make_int4(64, 64, N_GATES, -1);
            #pragma unroll
            for (int o = 0; o < N_OUTPUTS; ++o) owS[s * N_OUTPUTS + o] = 0.0f;
        }
    }
}

// ---------------------------------------------------------------------------
// Kernel 2: transpose X -> XT (feature-major, half2-packed along samples).
// Block = 64 threads = 64 words = 128 samples. Coalesced reads via LDS tile,
// coalesced 256B row writes. Rows 64/65 are const 0 / const 1.
// ---------------------------------------------------------------------------
__global__ __launch_bounds__(64) void transpose_kernel(
    const float* __restrict__ X,
    __half2*     __restrict__ XT)
{
    __shared__ __half2 sb[64 * 65];          // [feature][word], stride 65

    const int t  = threadIdx.x;
    const int w0 = blockIdx.x * 64;
    const float4* Xv = (const float4*)(X + (long long)w0 * 2 * N_FEATURES);

    #pragma unroll
    for (int k = 0; k < 16; ++k) {
        int q  = k * 64 + t;                 // (word j, float4-col c4) pair id
        int c4 = q & 15;
        int j  = q >> 4;
        float4 va = Xv[(2 * j)     * 16 + c4];
        float4 vb = Xv[(2 * j + 1) * 16 + c4];
        int c = c4 * 4;
        sb[(c + 0) * 65 + j] = __halves2half2(__float2half(va.x), __float2half(vb.x));
        sb[(c + 1) * 65 + j] = __halves2half2(__float2half(va.y), __float2half(vb.y));
        sb[(c + 2) * 65 + j] = __halves2half2(__float2half(va.z), __float2half(vb.z));
        sb[(c + 3) * 65 + j] = __halves2half2(__float2half(va.w), __float2half(vb.w));
    }
    __syncthreads();

    #pragma unroll
    for (int c = 0; c < N_FEATURES; ++c)
        XT[c * NWORDS + w0 + t] = sb[c * 65 + t];

    XT[64 * NWORDS + w0 + t] = __half2half2(__float2half(0.0f));
    XT[65 * NWORDS + w0 + t] = __half2half2(__float2half(1.0f));
}

// ---------------------------------------------------------------------------
// Kernel 3: circuit. LDS holds ONLY gate outputs: 65 rows x 64 words = 16.6 KB
// -> 9 blocks/CU (2.25 waves/SIMD vs 1 before). Features come from XT (coalesced,
// L3-resident, vmcnt-pipelined). Per chunk: 16 branchless dual reads, one wait,
// 8 computes+writes, 128 packed FMAs. No barriers (columns are thread-private).
// ---------------------------------------------------------------------------
template<bool USE_XT>
__global__ __launch_bounds__(64) void circuit_kernel(
    const float*   __restrict__ X,
    const __half2* __restrict__ XT,
    const int4*    __restrict__ slots,
    const float*   __restrict__ owS,
    const int*     __restrict__ nch,
    const float*   __restrict__ scale,
    float*         __restrict__ out)
{
    __shared__ __half2 gbuf[(N_GATES + 1) * 64];   // row 64 = dummy sink for pads

    const int t  = threadIdx.x;                    // 0..63, owns samples 2t,2t+1 of block
    const int wt = blockIdx.x * 64 + t;            // global half2-word index
    const long long s0 = (long long)blockIdx.x * 128;
    const int nchunks = *nch;

    v2f acc[N_OUTPUTS];
    #pragma unroll
    for (int o = 0; o < N_OUTPUTS; ++o) { acc[o].x = 0.0f; acc[o].y = 0.0f; }

    const __half2 one2 = __half2half2(__float2half(1.0f));

    for (int ch = 0; ch < nchunks; ++ch) {
        int4 rec[CH];
        #pragma unroll
        for (int k = 0; k < CH; ++k) rec[k] = slots[ch * CH + k];

        // ---- batched operand reads (all issue before any write of this chunk)
        __half2 av[CH], bv[CH];
        #pragma unroll
        for (int k = 0; k < CH; ++k) {
            const int ea = rec[k].x, eb = rec[k].y;
            if (USE_XT) {
                // branchless dual read + select (conditions are wave-uniform)
                int ca = (ea < BASE_COLS) ? ea : 0;
                int ra = (ea < BASE_COLS) ? N_GATES : (ea - BASE_COLS);
                __half2 xa = XT[ca * NWORDS + wt];
                __half2 la = gbuf[ra * 64 + t];
                av[k] = (ea < BASE_COLS) ? xa : la;

                int cb = (eb < BASE_COLS) ? eb : 0;
                int rb = (eb < BASE_COLS) ? N_GATES : (eb - BASE_COLS);
                __half2 xb = XT[cb * NWORDS + wt];
                __half2 lb = gbuf[rb * 64 + t];
                bv[k] = (eb < BASE_COLS) ? xb : lb;
            } else {
                // fallback (workspace too small for XT): features straight from X
                __half2 a, b;
                if (ea >= BASE_COLS)      a = gbuf[(ea - BASE_COLS) * 64 + t];
                else if (ea == 64)        a = __half2half2(__float2half(0.0f));
                else if (ea == 65)        a = __half2half2(__float2half(1.0f));
                else {
                    float f0 = X[(s0 + 2 * t)     * N_FEATURES + ea];
                    float f1 = X[(s0 + 2 * t + 1) * N_FEATURES + ea];
                    a = __halves2half2(__float2half(f0), __float2half(f1));
                }
                if (eb >= BASE_COLS)      b = gbuf[(eb - BASE_COLS) * 64 + t];
                else if (eb == 64)        b = __half2half2(__float2half(0.0f));
                else if (eb == 65)        b = __half2half2(__float2half(1.0f));
                else {
                    float f0 = X[(s0 + 2 * t)     * N_FEATURES + eb];
                    float f1 = X[(s0 + 2 * t + 1) * N_FEATURES + eb];
                    b = __halves2half2(__float2half(f0), __float2half(f1));
                }
                av[k] = a; bv[k] = b;
            }
        }

        // ---- compute + LDS write + packed accumulation
        #pragma unroll
        for (int k = 0; k < CH; ++k) {
            __half2 g = __hfma2(__hneg2(av[k]), bv[k], one2);   // 1 - a*b (2 samples)
            gbuf[rec[k].z * 64 + t] = g;                        // in-order DS => RAW safe
            v2f g2; g2.x = __low2float(g); g2.y = __high2float(g);
            const float* wp = owS + (ch * CH + k) * N_OUTPUTS;
            #pragma unroll
            for (int o = 0; o < N_OUTPUTS; ++o) {
                v2f wv; wv.x = wp[o]; wv.y = wp[o];
                acc[o] = __builtin_elementwise_fma(g2, wv, acc[o]);  // v_pk_fma_f32
            }
        }
    }

    // ---- epilogue: scale + coalesced store (64 B/lane)
    float sc[N_OUTPUTS];
    #pragma unroll
    for (int o = 0; o < N_OUTPUTS; ++o) sc[o] = scale[o];

    float4* outv = (float4*)(out + (s0 + 2 * t) * N_OUTPUTS);
    outv[0] = make_float4(acc[0].x * sc[0], acc[1].x * sc[1], acc[2].x * sc[2], acc[3].x * sc[3]);
    outv[1] = make_float4(acc[4].x * sc[4], acc[5].x * sc[5], acc[6].x * sc[6], acc[7].x * sc[7]);
    outv[2] = make_float4(acc[0].y * sc[0], acc[1].y * sc[1], acc[2].y * sc[2], acc[3].y * sc[3]);
    outv[3] = make_float4(acc[4].y * sc[4], acc[5].y * sc[5], acc[6].y * sc[6], acc[7].y * sc[7]);
}

extern "C" void kernel_launch(void* const* d_in, const int* in_sizes, int n_in,
                              void* d_out, int out_size, void* d_ws, size_t ws_size,
                              hipStream_t stream)
{
    const float* X     = (const float*)d_in[0];  // [524288][64]
    const float* gw    = (const float*)d_in[1];  // [64][130]
    const float* ow    = (const float*)d_in[2];  // [64][8]
    const float* scale = (const float*)d_in[3];  // [8]
    float* out = (float*)d_out;                  // [524288][8]

    char* ws = (char*)d_ws;
    int4*    slots = (int4*)ws;                       // 512 * 16 B = 8192 B
    float*   owS   = (float*)(ws + 8192);             // 512 * 8 * 4 B = 16384 B
    int*     nch   = (int*)(ws + 8192 + 16384);       // 4 B
    __half2* XT    = (__half2*)(ws + 32768);          // 66 * 262144 * 4 B = 69.2 MB
    const size_t xt_bytes = (size_t)XT_ROWS * NWORDS * sizeof(__half2);
    const bool use_xt = ws_size >= (size_t)32768 + xt_bytes;

    plan_kernel<<<1, 64, 0, stream>>>(gw, ow, slots, owS, nch);

    const int blocks = N_SAMPLES / 128;               // 4096
    if (use_xt) {
        transpose_kernel<<<blocks, 64, 0, stream>>>(X, XT);
        circuit_kernel<true><<<blocks, 64, 0, stream>>>(X, XT, slots, owS, nch, scale, out);
    } else {
        circuit_kernel<false><<<blocks, 64, 0, stream>>>(X, XT, slots, owS, nch, scale, out);
    }
}

// Round 2
// 310.404 us; speedup vs baseline: 1.8252x; 1.8252x over previous
//
#include <hip/hip_runtime.h>
#include <hip/hip_fp16.h>

// Problem constants (from reference)
#define N_SAMPLES 524288
#define N_FEATURES 64
#define N_GATES 64
#define N_OUTPUTS 8
#define BASE_COLS 66          // N_FEATURES + 2 (zero col, one col)
#define MAX_CONN 130          // BASE + N_GATES

#define NWORDS (N_SAMPLES / 2)   // 262144 half2 words per XT row (2 samples/word)
#define CH 8                     // gates per schedule chunk
#define MAXSLOTS 512             // worst case: 64 levels x 8 padded slots
#define GWS_STR 131              // LDS stride for gate weights (break bank pattern)

typedef float v2f __attribute__((ext_vector_type(2)));

// ---------------------------------------------------------------------------
// top-2 insert, tie-break lower index (matches jax.lax.top_k stable order)
// ---------------------------------------------------------------------------
__device__ __forceinline__ void top2_ins(float x, int j, float& v1, int& i1, float& v2, int& i2) {
    bool gt1 = (x > v1) || (x == v1 && j < i1);
    bool gt2 = (x > v2) || (x == v2 && j < i2);
    if (gt1) { v2 = v1; i2 = i1; v1 = x; i1 = j; }
    else if (gt2) { v2 = x; i2 = j; }
}

// ---------------------------------------------------------------------------
// Kernel 1: plan (ONE wave, lane = gate).
//  - stage gate weights to LDS (coalesced), per-lane serial top-2 scan
//  - dataflow level via parallel relaxation (shfl from predecessor lanes)
//  - slot index via ballot/popcount prefix; levels padded to multiples of CH
// Emits slots[s] = {encA, encB, ldsWriteRow, gate(-1 pad)} and *nch.
// Encoding: e<64 -> XT feature row e; 64 -> const0; 65 -> const1; e>=66 -> gate e-66.
// ---------------------------------------------------------------------------
__global__ __launch_bounds__(64) void plan_kernel(
    const float* __restrict__ gw,
    int4* __restrict__ slots,
    int*  __restrict__ nch)
{
    __shared__ float gws[N_GATES * GWS_STR];   // 33,536 B
    __shared__ int4  rec[MAXSLOTS];            //  8,192 B

    const int l = threadIdx.x;                 // lane == gate id

    // ---- stage all gate weights to LDS, coalesced global reads
    for (int k = l; k < N_GATES * MAX_CONN; k += 64) {
        int gi = k / MAX_CONN;
        int jj = k - gi * MAX_CONN;
        gws[gi * GWS_STR + jj] = gw[k];
    }
    __syncthreads();

    // ---- per-lane serial top-2 over this gate's valid columns
    const int avail = BASE_COLS + l;
    float v1 = -1e30f, v2 = -1e30f;
    int   i1 = 0x7fffffff, i2 = 0x7fffffff;
    const float* w = gws + l * GWS_STR;
    for (int j = 0; j < avail; ++j)
        top2_ins(w[j], j, v1, i1, v2, i2);

    // ---- dataflow level: parallel relaxation (preds always have smaller gate id)
    const bool ga = (i1 >= BASE_COLS), gb = (i2 >= BASE_COLS);
    const int  pa = ga ? (i1 - BASE_COLS) : 0;
    const int  pb = gb ? (i2 - BASE_COLS) : 0;
    int lvl = 0;
    bool changed = true;
    while (__any(changed)) {
        int la = __shfl(lvl, pa);
        int lb = __shfl(lvl, pb);
        int nl = lvl;
        if (ga && la + 1 > nl) nl = la + 1;
        if (gb && lb + 1 > nl) nl = lb + 1;
        changed = (nl != lvl);
        lvl = nl;
    }

    // ---- slot assignment: levels in order, each padded to a multiple of CH
    int myslot = 0, running = 0, assigned = 0;
    for (int L = 0; assigned < N_GATES; ++L) {
        unsigned long long mask = __ballot(lvl == L);
        int c = __popcll(mask);
        if (c) {
            if (lvl == L) {
                int pos = __popcll(mask & ((1ull << l) - 1ull));
                myslot = running + pos;
            }
            running += (c + CH - 1) & ~(CH - 1);
            assigned += c;
        }
    }
    const int ns = running;                    // <= MAXSLOTS

    // ---- fill pads, scatter real records, copy out
    for (int s = l; s < ns; s += 64)
        rec[s] = make_int4(64, 64, N_GATES, -1);   // pad: const0*const0 -> dummy row
    __syncthreads();
    rec[myslot] = make_int4(i1, i2, l, l);
    __syncthreads();

    for (int s = l; s < ns; s += 64)
        slots[s] = rec[s];
    if (l == 0) *nch = ns / CH;
}

// ---------------------------------------------------------------------------
// Kernel 2: transpose X -> XT (feature-major, half2-packed along samples).
// Block = 64 threads = 64 words = 128 samples. Coalesced float4 reads via LDS
// tile, coalesced 256B row writes. Const rows are handled in-register by the
// circuit kernel (not materialized).
// ---------------------------------------------------------------------------
__global__ __launch_bounds__(64) void transpose_kernel(
    const float* __restrict__ X,
    __half2*     __restrict__ XT)
{
    __shared__ __half2 sb[64 * 65];          // [feature][word], stride 65

    const int t  = threadIdx.x;
    const int w0 = blockIdx.x * 64;
    const float4* Xv = (const float4*)(X + (long long)w0 * 2 * N_FEATURES);

    #pragma unroll
    for (int k = 0; k < 16; ++k) {
        int q  = k * 64 + t;                 // (word j, float4-col c4) pair id
        int c4 = q & 15;
        int j  = q >> 4;
        float4 va = Xv[(2 * j)     * 16 + c4];
        float4 vb = Xv[(2 * j + 1) * 16 + c4];
        int c = c4 * 4;
        sb[(c + 0) * 65 + j] = __halves2half2(__float2half(va.x), __float2half(vb.x));
        sb[(c + 1) * 65 + j] = __halves2half2(__float2half(va.y), __float2half(vb.y));
        sb[(c + 2) * 65 + j] = __halves2half2(__float2half(va.z), __float2half(vb.z));
        sb[(c + 3) * 65 + j] = __halves2half2(__float2half(va.w), __float2half(vb.w));
    }
    __syncthreads();

    #pragma unroll
    for (int c = 0; c < N_FEATURES; ++c)
        XT[c * NWORDS + w0 + t] = sb[c * 65 + t];
}

// ---------------------------------------------------------------------------
// Operand fetch: e is wave-uniform (SGPR) -> scalar branches, single load.
// ---------------------------------------------------------------------------
__device__ __forceinline__ __half2 fetch_xt(int e, const __half2* __restrict__ XT,
                                            const __half2* gbuf, int t, int wt)
{
    if (e >= BASE_COLS) return gbuf[(e - BASE_COLS) * 64 + t];
    if (e == 64)        return __half2half2(__float2half(0.0f));
    if (e == 65)        return __half2half2(__float2half(1.0f));
    return XT[e * NWORDS + wt];
}

__device__ __forceinline__ __half2 fetch_x(int e, const float* __restrict__ X,
                                           const __half2* gbuf, long long s0, int t)
{
    if (e >= BASE_COLS) return gbuf[(e - BASE_COLS) * 64 + t];
    if (e == 64)        return __half2half2(__float2half(0.0f));
    if (e == 65)        return __half2half2(__float2half(1.0f));
    float f0 = X[(s0 + 2 * t)     * N_FEATURES + e];
    float f1 = X[(s0 + 2 * t + 1) * N_FEATURES + e];
    return __halves2half2(__float2half(f0), __float2half(f1));
}

// ---------------------------------------------------------------------------
// Kernel 3: circuit. LDS = gate outputs only (65 rows x 64 words = 16.6 KB ->
// 9 blocks/CU). Chunk loop: 16 scalar-branched fetches batched, 8 hfma2,
// 8 ds_write. Output GEMV done ONCE at the end over gates 0..63 (reference
// summation order, no pad FMAs). No barriers (columns are thread-private).
// ---------------------------------------------------------------------------
template<bool USE_XT>
__global__ __launch_bounds__(64) void circuit_kernel(
    const float*   __restrict__ X,
    const __half2* __restrict__ XT,
    const int4*    __restrict__ slots,
    const int*     __restrict__ nch,
    const float*   __restrict__ ow,     // [N_GATES][N_OUTPUTS]
    const float*   __restrict__ scale,  // [N_OUTPUTS]
    float*         __restrict__ out)    // [N_SAMPLES][N_OUTPUTS]
{
    __shared__ __half2 gbuf[(N_GATES + 1) * 64];   // row 64 = dummy sink for pads

    const int t  = threadIdx.x;                    // 0..63, owns samples 2t,2t+1
    const int wt = blockIdx.x * 64 + t;            // global half2-word index
    const long long s0 = (long long)blockIdx.x * 128;
    const int nchunks = __builtin_amdgcn_readfirstlane(*nch);

    const __half2 one2 = __half2half2(__float2half(1.0f));

    for (int ch = 0; ch < nchunks; ++ch) {
        __half2 av[CH], bv[CH];
        int wr[CH];
        #pragma unroll
        for (int k = 0; k < CH; ++k) {
            int4 r = slots[ch * CH + k];
            int ea = __builtin_amdgcn_readfirstlane(r.x);
            int eb = __builtin_amdgcn_readfirstlane(r.y);
            wr[k]  = __builtin_amdgcn_readfirstlane(r.z);
            if (USE_XT) {
                av[k] = fetch_xt(ea, XT, gbuf, t, wt);
                bv[k] = fetch_xt(eb, XT, gbuf, t, wt);
            } else {
                av[k] = fetch_x(ea, X, gbuf, s0, t);
                bv[k] = fetch_x(eb, X, gbuf, s0, t);
            }
        }
        #pragma unroll
        for (int k = 0; k < CH; ++k) {
            __half2 gv = __hfma2(__hneg2(av[k]), bv[k], one2);  // 1 - a*b (2 samples)
            gbuf[wr[k] * 64 + t] = gv;                          // in-order DS => safe
        }
    }

    // ---- output GEMV over gates in reference order (no pads, no scheduling)
    v2f acc[N_OUTPUTS];
    #pragma unroll
    for (int o = 0; o < N_OUTPUTS; ++o) { acc[o].x = 0.0f; acc[o].y = 0.0f; }

    #pragma unroll 4
    for (int g = 0; g < N_GATES; ++g) {
        __half2 gv = gbuf[g * 64 + t];
        v2f g2; g2.x = __low2float(gv); g2.y = __high2float(gv);
        #pragma unroll
        for (int o = 0; o < N_OUTPUTS; ++o) {
            float w = ow[g * N_OUTPUTS + o];                    // uniform -> s_load
            v2f wv; wv.x = w; wv.y = w;
            acc[o] = __builtin_elementwise_fma(g2, wv, acc[o]); // v_pk_fma_f32
        }
    }

    // ---- epilogue: scale + coalesced store (64 B/lane)
    float sc[N_OUTPUTS];
    #pragma unroll
    for (int o = 0; o < N_OUTPUTS; ++o) sc[o] = scale[o];

    float4* outv = (float4*)(out + (s0 + 2 * t) * N_OUTPUTS);
    outv[0] = make_float4(acc[0].x * sc[0], acc[1].x * sc[1], acc[2].x * sc[2], acc[3].x * sc[3]);
    outv[1] = make_float4(acc[4].x * sc[4], acc[5].x * sc[5], acc[6].x * sc[6], acc[7].x * sc[7]);
    outv[2] = make_float4(acc[0].y * sc[0], acc[1].y * sc[1], acc[2].y * sc[2], acc[3].y * sc[3]);
    outv[3] = make_float4(acc[4].y * sc[4], acc[5].y * sc[5], acc[6].y * sc[6], acc[7].y * sc[7]);
}

extern "C" void kernel_launch(void* const* d_in, const int* in_sizes, int n_in,
                              void* d_out, int out_size, void* d_ws, size_t ws_size,
                              hipStream_t stream)
{
    const float* X     = (const float*)d_in[0];  // [524288][64]
    const float* gw    = (const float*)d_in[1];  // [64][130]
    const float* ow    = (const float*)d_in[2];  // [64][8]
    const float* scale = (const float*)d_in[3];  // [8]
    float* out = (float*)d_out;                  // [524288][8]

    char* ws = (char*)d_ws;
    int4*    slots = (int4*)ws;                       // 512 * 16 B = 8192 B
    int*     nch   = (int*)(ws + 8192);               // 4 B
    __half2* XT    = (__half2*)(ws + 32768);          // 64 * 262144 * 4 B = 64 MiB
    const size_t xt_bytes = (size_t)N_FEATURES * NWORDS * sizeof(__half2);
    const bool use_xt = ws_size >= (size_t)32768 + xt_bytes;

    plan_kernel<<<1, 64, 0, stream>>>(gw, slots, nch);

    const int blocks = N_SAMPLES / 128;               // 4096
    if (use_xt) {
        transpose_kernel<<<blocks, 64, 0, stream>>>(X, XT);
        circuit_kernel<true><<<blocks, 64, 0, stream>>>(X, XT, slots, nch, ow, scale, out);
    } else {
        circuit_kernel<false><<<blocks, 64, 0, stream>>>(X, XT, slots, nch, ow, scale, out);
    }
}

// Round 3
// 270.966 us; speedup vs baseline: 2.0909x; 1.1455x over previous
//
#include <hip/hip_runtime.h>
#include <hip/hip_fp16.h>

// Problem constants (from reference)
#define N_SAMPLES 524288
#define N_FEATURES 64
#define N_GATES 64
#define N_OUTPUTS 8
#define BASE_COLS 66          // N_FEATURES + 2 (zero col, one col)
#define MAX_CONN 130          // BASE + N_GATES

#define CH 8                  // gates per schedule chunk
#define MAXSLOTS 512          // worst case: 64 levels x 8 padded slots
#define GWS_STR 131           // plan LDS stride (131%32=3 -> 2-way banks, free)
#define FB_STR 65             // feature-buffer stride in half2 words (65%32=1 -> 2-way)

typedef float v2f __attribute__((ext_vector_type(2)));

// ---------------------------------------------------------------------------
// top-2 insert, tie-break lower index (matches jax.lax.top_k stable order).
// Order-independent: equal values resolved by explicit index compare.
// ---------------------------------------------------------------------------
__device__ __forceinline__ void top2_ins(float x, int j, float& v1, int& i1, float& v2, int& i2) {
    bool gt1 = (x > v1) || (x == v1 && j < i1);
    bool gt2 = (x > v2) || (x == v2 && j < i2);
    if (gt1) { v2 = v1; i2 = i1; v1 = x; i1 = j; }
    else if (gt2) { v2 = x; i2 = j; }
}

// ---------------------------------------------------------------------------
// Kernel 1: plan (256 threads).
//  phase 1: float4-staged gate weights -> LDS (stride 131)
//  phase 2: thread (gate g, strip s) partial top-2 over 33 columns (4 strips)
//  phase 3: wave 0 merges strips, relaxes dataflow levels (shfl), assigns
//           slots via ballot prefix (levels padded to multiples of CH)
// Emits packed slots[s] = ea | eb<<8 | wr<<16  and *nch.
// Encoding: e<64 -> feature e; 64 -> const0; 65 -> const1; e>=66 -> gate e-66.
// ---------------------------------------------------------------------------
__global__ __launch_bounds__(256) void plan_kernel(
    const float* __restrict__ gw,
    int* __restrict__ slots,
    int* __restrict__ nch)
{
    __shared__ float gws[N_GATES * GWS_STR];            // 33,536 B
    __shared__ float pv1[4][N_GATES], pv2[4][N_GATES];  // 2 KB
    __shared__ int   pi1[4][N_GATES], pi2[4][N_GATES];  // 2 KB
    __shared__ int   rec[MAXSLOTS];                     // 2 KB

    const int tid = threadIdx.x;

    // ---- phase 1: stage 64x130 floats, vectorized + coalesced
    const float4* gw4 = (const float4*)gw;              // 2080 float4s
    for (int k = tid; k < (N_GATES * MAX_CONN) / 4; k += 256) {
        float4 v = gw4[k];
        int base = 4 * k;
        #pragma unroll
        for (int e = 0; e < 4; ++e) {
            int idx = base + e;
            int gi  = idx / MAX_CONN;
            int jj  = idx - gi * MAX_CONN;
            gws[gi * GWS_STR + jj] = (&v.x)[e];
        }
    }
    __syncthreads();

    // ---- phase 2: partial top-2, one strip of ~33 columns per thread
    {
        const int g = tid & 63, s = tid >> 6;
        const int avail = BASE_COLS + g;
        int j0 = s * 33;
        int j1 = j0 + 33; if (j1 > avail) j1 = avail;
        float v1 = -1e30f, v2 = -1e30f;
        int   i1 = 0x7fffffff, i2 = 0x7fffffff;
        const float* w = gws + g * GWS_STR;
        for (int j = j0; j < j1; ++j)
            top2_ins(w[j], j, v1, i1, v2, i2);
        pv1[s][g] = v1; pi1[s][g] = i1;
        pv2[s][g] = v2; pi2[s][g] = i2;
    }
    __syncthreads();

    if (tid >= 64) return;          // wave 0 finishes alone (no barriers below)
    const int l = tid;              // lane == gate id

    // ---- merge 4 strip partials
    float v1 = -1e30f, v2 = -1e30f;
    int   i1 = 0x7fffffff, i2 = 0x7fffffff;
    #pragma unroll
    for (int s = 0; s < 4; ++s) {
        top2_ins(pv1[s][l], pi1[s][l], v1, i1, v2, i2);
        top2_ins(pv2[s][l], pi2[s][l], v1, i1, v2, i2);
    }

    // ---- dataflow level: parallel relaxation (preds have smaller gate id)
    const bool ga = (i1 >= BASE_COLS), gb = (i2 >= BASE_COLS);
    const int  pa = ga ? (i1 - BASE_COLS) : 0;
    const int  pb = gb ? (i2 - BASE_COLS) : 0;
    int lvl = 0;
    bool changed = true;
    while (__any(changed)) {
        int la = __shfl(lvl, pa);
        int lb = __shfl(lvl, pb);
        int nl = lvl;
        if (ga && la + 1 > nl) nl = la + 1;
        if (gb && lb + 1 > nl) nl = lb + 1;
        changed = (nl != lvl);
        lvl = nl;
    }

    // ---- slot assignment: levels in order, padded to multiples of CH
    int myslot = 0, running = 0, assigned = 0;
    for (int L = 0; assigned < N_GATES; ++L) {
        unsigned long long mask = __ballot(lvl == L);
        int c = __popcll(mask);
        if (c) {
            if (lvl == L) {
                int pos = __popcll(mask & ((1ull << l) - 1ull));
                myslot = running + pos;
            }
            running += (c + CH - 1) & ~(CH - 1);
            assigned += c;
        }
    }
    const int ns = running;         // uniform across wave, <= MAXSLOTS

    // ---- pads, scatter, copy out (same-wave DS ops are in-order -> safe)
    const int pad = 64 | (64 << 8) | (64 << 16);   // const0*const0 -> dummy row
    for (int q = l; q < ns; q += 64) rec[q] = pad;
    rec[myslot] = i1 | (i2 << 8) | (l << 16);
    for (int q = l; q < ns; q += 64) slots[q] = rec[q];
    if (l == 0) *nch = ns / CH;
}

// ---------------------------------------------------------------------------
// Kernel 2: circuit, fully self-contained (no XT workspace, no transpose).
// One wave per block, 128 samples (lane owns samples 2t, 2t+1).
// LDS: fbuf 64 feature rows (stride 65, fp16x2) + gbuf 65 gate rows = 33 KB
// -> 4 blocks/CU. Staging verified conflict-free (2-way max). Chunk loop is
// pure-LDS: 16 independent ds_reads -> one wait -> 8 hfma2 -> 8 ds_write.
// No barriers after staging (single wave). Output GEMV once at the end.
// ---------------------------------------------------------------------------
__global__ __launch_bounds__(64) void circuit_kernel(
    const float* __restrict__ X,
    const int*   __restrict__ slots,
    const int*   __restrict__ nch,
    const float* __restrict__ ow,     // [N_GATES][N_OUTPUTS]
    const float* __restrict__ scale,  // [N_OUTPUTS]
    float*       __restrict__ out)    // [N_SAMPLES][N_OUTPUTS]
{
    __shared__ __half2 fbuf[N_FEATURES * FB_STR];   // 16,640 B
    __shared__ __half2 gbuf[(N_GATES + 1) * 64];    // 16,640 B (row 64 = pad sink)

    const int t = threadIdx.x;                      // 0..63
    const long long s0 = (long long)blockIdx.x * 128;

    // ---- stage X chunk (128 samples x 64 feats) -> fbuf, transposed fp16x2.
    // task q = k*64+t: c4 = q&15 (float4 col), j = q>>4 (half2 word 0..63).
    const float4* Xv = (const float4*)(X + s0 * N_FEATURES);
    #pragma unroll
    for (int k = 0; k < 16; ++k) {
        int q  = k * 64 + t;
        int c4 = q & 15;
        int j  = q >> 4;
        float4 va = Xv[(2 * j)     * 16 + c4];
        float4 vb = Xv[(2 * j + 1) * 16 + c4];
        int c = 4 * c4;
        fbuf[(c + 0) * FB_STR + j] = __halves2half2(__float2half(va.x), __float2half(vb.x));
        fbuf[(c + 1) * FB_STR + j] = __halves2half2(__float2half(va.y), __float2half(vb.y));
        fbuf[(c + 2) * FB_STR + j] = __halves2half2(__float2half(va.z), __float2half(vb.z));
        fbuf[(c + 3) * FB_STR + j] = __halves2half2(__float2half(va.w), __float2half(vb.w));
    }
    __syncthreads();

    const int nchunks = __builtin_amdgcn_readfirstlane(*nch);
    const __half2 one2  = __half2half2(__float2half(1.0f));
    const __half2 zero2 = __half2half2(__float2half(0.0f));

    const int4* sl4 = (const int4*)slots;
    for (int ch = 0; ch < nchunks; ++ch) {
        int4 wa = sl4[ch * 2];
        int4 wb = sl4[ch * 2 + 1];
        int sl[CH] = {wa.x, wa.y, wa.z, wa.w, wb.x, wb.y, wb.z, wb.w};

        __half2 av[CH], bv[CH];
        int wr[CH];
        #pragma unroll
        for (int k = 0; k < CH; ++k) {
            int sv = __builtin_amdgcn_readfirstlane(sl[k]);
            int ea =  sv        & 255;
            int eb = (sv >> 8)  & 255;
            wr[k]  = (sv >> 16) & 255;
            // scalar (SGPR) branches -> single load each, no divergence
            av[k] = (ea >= BASE_COLS) ? gbuf[(ea - BASE_COLS) * 64 + t]
                  : (ea == 64)        ? zero2
                  : (ea == 65)        ? one2
                                      : fbuf[ea * FB_STR + t];
            bv[k] = (eb >= BASE_COLS) ? gbuf[(eb - BASE_COLS) * 64 + t]
                  : (eb == 64)        ? zero2
                  : (eb == 65)        ? one2
                                      : fbuf[eb * FB_STR + t];
        }
        #pragma unroll
        for (int k = 0; k < CH; ++k) {
            __half2 gv = __hfma2(__hneg2(av[k]), bv[k], one2);  // 1 - a*b
            gbuf[wr[k] * 64 + t] = gv;                          // in-order DS
        }
    }

    // ---- output GEMV over gates 0..63 (reference order, no pads)
    v2f acc[N_OUTPUTS];
    #pragma unroll
    for (int o = 0; o < N_OUTPUTS; ++o) { acc[o].x = 0.0f; acc[o].y = 0.0f; }

    #pragma unroll 4
    for (int g = 0; g < N_GATES; ++g) {
        __half2 gv = gbuf[g * 64 + t];
        v2f g2; g2.x = __low2float(gv); g2.y = __high2float(gv);
        #pragma unroll
        for (int o = 0; o < N_OUTPUTS; ++o) {
            float w = ow[g * N_OUTPUTS + o];                    // uniform -> s_load
            v2f wv; wv.x = w; wv.y = w;
            acc[o] = __builtin_elementwise_fma(g2, wv, acc[o]); // v_pk_fma_f32
        }
    }

    // ---- epilogue: scale + coalesced store (64 B/lane)
    float sc[N_OUTPUTS];
    #pragma unroll
    for (int o = 0; o < N_OUTPUTS; ++o) sc[o] = scale[o];

    float4* outv = (float4*)(out + (s0 + 2 * t) * N_OUTPUTS);
    outv[0] = make_float4(acc[0].x * sc[0], acc[1].x * sc[1], acc[2].x * sc[2], acc[3].x * sc[3]);
    outv[1] = make_float4(acc[4].x * sc[4], acc[5].x * sc[5], acc[6].x * sc[6], acc[7].x * sc[7]);
    outv[2] = make_float4(acc[0].y * sc[0], acc[1].y * sc[1], acc[2].y * sc[2], acc[3].y * sc[3]);
    outv[3] = make_float4(acc[4].y * sc[4], acc[5].y * sc[5], acc[6].y * sc[6], acc[7].y * sc[7]);
}

extern "C" void kernel_launch(void* const* d_in, const int* in_sizes, int n_in,
                              void* d_out, int out_size, void* d_ws, size_t ws_size,
                              hipStream_t stream)
{
    const float* X     = (const float*)d_in[0];  // [524288][64]
    const float* gw    = (const float*)d_in[1];  // [64][130]
    const float* ow    = (const float*)d_in[2];  // [64][8]
    const float* scale = (const float*)d_in[3];  // [8]
    float* out = (float*)d_out;                  // [524288][8]

    char* ws  = (char*)d_ws;
    int* slots = (int*)ws;                       // 512 * 4 B = 2048 B
    int* nch   = (int*)(ws + 2048);              // 4 B

    plan_kernel<<<1, 256, 0, stream>>>(gw, slots, nch);

    const int blocks = N_SAMPLES / 128;          // 4096
    circuit_kernel<<<blocks, 64, 0, stream>>>(X, slots, nch, ow, scale, out);
}

// Round 4
// 233.013 us; speedup vs baseline: 2.4314x; 1.1629x over previous
//
#include <hip/hip_runtime.h>
#include <hip/hip_fp16.h>

// Problem constants (from reference)
#define N_SAMPLES 524288
#define N_FEATURES 64
#define N_GATES 64
#define N_OUTPUTS 8
#define BASE_COLS 66          // N_FEATURES + 2 (zero col, one col)
#define MAX_CONN 130          // BASE + N_GATES

#define NWAVES 4              // waves per circuit block
#define MAXW 192              // stream ints per wave (worst case 130)
#define ROWS 131              // 0-63 feat, 64 c0, 65 c1, 66-129 gates, 130 dummy
#define GWS_STR 131           // plan LDS stride for gate weights
#define PAD_SLOT (64 | (64 << 8) | (130 << 16))   // const0*const0 -> dummy row

typedef float v2f __attribute__((ext_vector_type(2)));

// ---------------------------------------------------------------------------
// top-2 insert, tie-break lower index (matches jax.lax.top_k stable order)
// ---------------------------------------------------------------------------
__device__ __forceinline__ void top2_ins(float x, int j, float& v1, int& i1, float& v2, int& i2) {
    bool gt1 = (x > v1) || (x == v1 && j < i1);
    bool gt2 = (x > v2) || (x == v2 && j < i2);
    if (gt1) { v2 = v1; i2 = i1; v1 = x; i1 = j; }
    else if (gt2) { v2 = x; i2 = j; }
}

// ---------------------------------------------------------------------------
// Kernel 1: plan (256 threads). Top-2 per gate (strip-parallel), dataflow
// levels (shfl relaxation), then emits 4 per-wave instruction streams:
//   slot int = rowA | rowB<<8 | wrRow<<16 | gateId<<24   (>= 0)
//   -1 = level barrier, -2 = end of stream.
// Each level's gates are split round-robin over 4 waves, padded so all
// streams have identical structure (uniform barrier counts).
// ---------------------------------------------------------------------------
__global__ __launch_bounds__(256) void plan_kernel(
    const float* __restrict__ gw,
    int* __restrict__ stream)             // [NWAVES][MAXW]
{
    __shared__ float gws[N_GATES * GWS_STR];            // 33,536 B
    __shared__ float pv1[4][N_GATES], pv2[4][N_GATES];  // 2 KB
    __shared__ int   pi1[4][N_GATES], pi2[4][N_GATES];  // 2 KB
    __shared__ int   streamL[NWAVES * MAXW];            // 3 KB

    const int tid = threadIdx.x;

    // ---- stage 64x130 gate weights, vectorized + coalesced
    const float4* gw4 = (const float4*)gw;              // 2080 float4s
    for (int k = tid; k < (N_GATES * MAX_CONN) / 4; k += 256) {
        float4 v = gw4[k];
        int base = 4 * k;
        #pragma unroll
        for (int e = 0; e < 4; ++e) {
            int idx = base + e;
            int gi  = idx / MAX_CONN;
            int jj  = idx - gi * MAX_CONN;
            gws[gi * GWS_STR + jj] = (&v.x)[e];
        }
    }
    __syncthreads();

    // ---- partial top-2: thread (gate g, strip s), ~33 columns each
    {
        const int g = tid & 63, s = tid >> 6;
        const int avail = BASE_COLS + g;
        int j0 = s * 33;
        int j1 = j0 + 33; if (j1 > avail) j1 = avail;
        float v1 = -1e30f, v2 = -1e30f;
        int   i1 = 0x7fffffff, i2 = 0x7fffffff;
        const float* w = gws + g * GWS_STR;
        for (int j = j0; j < j1; ++j)
            top2_ins(w[j], j, v1, i1, v2, i2);
        pv1[s][g] = v1; pi1[s][g] = i1;
        pv2[s][g] = v2; pi2[s][g] = i2;
    }
    __syncthreads();

    if (tid >= 64) return;              // wave 0 finishes alone
    const int l = tid;                  // lane == gate id

    // ---- merge strip partials
    float v1 = -1e30f, v2 = -1e30f;
    int   i1 = 0x7fffffff, i2 = 0x7fffffff;
    #pragma unroll
    for (int s = 0; s < 4; ++s) {
        top2_ins(pv1[s][l], pi1[s][l], v1, i1, v2, i2);
        top2_ins(pv2[s][l], pi2[s][l], v1, i1, v2, i2);
    }

    // ---- dataflow level: parallel relaxation (preds have smaller gate id)
    const bool ga = (i1 >= BASE_COLS), gb = (i2 >= BASE_COLS);
    const int  pa = ga ? (i1 - BASE_COLS) : 0;
    const int  pb = gb ? (i2 - BASE_COLS) : 0;
    int lvl = 0;
    bool changed = true;
    while (__any(changed)) {
        int la = __shfl(lvl, pa);
        int lb = __shfl(lvl, pb);
        int nl = lvl;
        if (ga && la + 1 > nl) nl = la + 1;
        if (gb && lb + 1 > nl) nl = lb + 1;
        changed = (nl != lvl);
        lvl = nl;
    }

    // ---- default-fill streams with END (-2); in-order DS makes later
    //      overwrites safe within the single wave.
    for (int q = l; q < NWAVES * MAXW; q += 64) streamL[q] = -2;

    // ---- per-level: pads + barrier sentinels, record own position
    int p_base = 0, assigned = 0;
    int myW = 0, myP = 0;
    for (int L = 0; L < 64 && assigned < 64; ++L) {
        unsigned long long mask = __ballot(lvl == L);
        int c = __popcll(mask);
        if (!c) continue;
        int m = (c + NWAVES - 1) >> 2;           // steps this level
        if (lvl == L) {
            int r = __popcll(mask & ((1ull << l) - 1ull));
            myW = r & 3; myP = p_base + (r >> 2);
        }
        if (l <= m) {
            int val = (l == m) ? -1 : PAD_SLOT;
            #pragma unroll
            for (int wv = 0; wv < NWAVES; ++wv)
                streamL[wv * MAXW + p_base + l] = val;
        }
        p_base += m + 1;
        assigned += c;
    }

    // ---- scatter real slots (overwrite pads; same-wave DS is in-order)
    streamL[myW * MAXW + myP] = i1 | (i2 << 8) | ((BASE_COLS + l) << 16) | (l << 24);

    // ---- copy out
    for (int q = l; q < NWAVES * MAXW; q += 64) stream[q] = streamL[q];
}

// ---------------------------------------------------------------------------
// Kernel 2: circuit. 256 threads = 4 waves SHARING one 131-row LDS buffer for
// the same 128 samples (33.5 KB -> 4 blocks/CU = 16 waves/CU, 4/SIMD).
// Each wave executes its private stream (preloaded into 3 VGPRs, fetched via
// v_readlane with uniform index); levels separated by __syncthreads().
// Rows swizzled: word w of row r lives at r*64 + (w ^ (r&31)) -> staging
// writes, row reads and gate writes are all bank-conflict-free.
// Incremental per-wave GEMV; cross-wave reduce in dead feature-row LDS.
// ---------------------------------------------------------------------------
__global__ __launch_bounds__(256, 4) void circuit_kernel(
    const float* __restrict__ X,
    const int*   __restrict__ stream,   // [NWAVES][MAXW]
    const float* __restrict__ ow,       // [N_GATES][N_OUTPUTS]
    const float* __restrict__ scale,    // [N_OUTPUTS]
    float*       __restrict__ out)      // [N_SAMPLES][N_OUTPUTS]
{
    __shared__ __half2 buf[ROWS * 64];  // 33,536 B

    const int tid = threadIdx.x;
    const int w = tid >> 6, t = tid & 63;
    const long long s0 = (long long)blockIdx.x * 128;

    // ---- preload this wave's stream into 3 VGPRs (covers MAXW=192)
    const int* st = stream + w * MAXW;
    const int sv0 = st[t], sv1 = st[64 + t], sv2 = st[128 + t];

    // ---- stage X chunk (128 samples x 64 feats) -> swizzled fp16x2 rows.
    // 1024 tasks: q = k*256+tid, c4 = q&15 (float4 col), j = q>>4 (word).
    const float4* Xv = (const float4*)(X + s0 * N_FEATURES);
    #pragma unroll
    for (int k = 0; k < 4; ++k) {
        int q  = k * 256 + tid;
        int c4 = q & 15;
        int j  = q >> 4;
        float4 va = Xv[(2 * j)     * 16 + c4];
        float4 vb = Xv[(2 * j + 1) * 16 + c4];
        int c = 4 * c4;
        buf[(c + 0) * 64 + (j ^ ((c + 0) & 31))] = __halves2half2(__float2half(va.x), __float2half(vb.x));
        buf[(c + 1) * 64 + (j ^ ((c + 1) & 31))] = __halves2half2(__float2half(va.y), __float2half(vb.y));
        buf[(c + 2) * 64 + (j ^ ((c + 2) & 31))] = __halves2half2(__float2half(va.z), __float2half(vb.z));
        buf[(c + 3) * 64 + (j ^ ((c + 3) & 31))] = __halves2half2(__float2half(va.w), __float2half(vb.w));
    }
    if (tid < 64)        buf[64 * 64 + tid]              = __half2half2(__float2half(0.0f)); // row 64 (xor 0)
    else if (tid < 128)  buf[65 * 64 + ((tid - 64) ^ 1)] = __half2half2(__float2half(1.0f)); // row 65 (xor 1)
    __syncthreads();

    const __half2 one2 = __half2half2(__float2half(1.0f));
    v2f acc[N_OUTPUTS];
    #pragma unroll
    for (int o = 0; o < N_OUTPUTS; ++o) { acc[o].x = 0.0f; acc[o].y = 0.0f; }

    // ---- stream interpreter: slots + level barriers
    int p = 0;
    while (true) {
        int sv = (p < 64)  ? __builtin_amdgcn_readlane(sv0, p)
               : (p < 128) ? __builtin_amdgcn_readlane(sv1, p - 64)
                           : __builtin_amdgcn_readlane(sv2, p - 128);
        ++p;
        if (sv < 0) {
            if (sv == -1) { __syncthreads(); continue; }   // level boundary
            break;                                          // -2: end
        }
        const int ra  =  sv        & 255;
        const int rb  = (sv >> 8)  & 255;
        const int wrr = (sv >> 16) & 255;
        const int gid = (sv >> 24) & 127;
        __half2 a = buf[ra * 64 + (t ^ (ra & 31))];
        __half2 b = buf[rb * 64 + (t ^ (rb & 31))];
        __half2 gv = __hfma2(__hneg2(a), b, one2);          // 1 - a*b (2 samples)
        buf[wrr * 64 + (t ^ (wrr & 31))] = gv;
        if (wrr != 130) {                                   // real gate: accumulate
            v2f g2; g2.x = __low2float(gv); g2.y = __high2float(gv);
            #pragma unroll
            for (int o = 0; o < N_OUTPUTS; ++o) {
                float wt = ow[gid * N_OUTPUTS + o];          // uniform -> s_load
                v2f wv; wv.x = wt; wv.y = wt;
                acc[o] = __builtin_elementwise_fma(g2, wv, acc[o]);
            }
        }
    }

    // ---- cross-wave reduction in dead feature-row region (16 KB)
    __syncthreads();
    float2* red = (float2*)buf;
    #pragma unroll
    for (int o = 0; o < N_OUTPUTS; ++o) {
        float2 v; v.x = acc[o].x; v.y = acc[o].y;
        red[(w * N_OUTPUTS + o) * 64 + t] = v;
    }
    __syncthreads();

    if (w == 0) {
        float sc[N_OUTPUTS];
        #pragma unroll
        for (int o = 0; o < N_OUTPUTS; ++o) sc[o] = scale[o];

        v2f s[N_OUTPUTS];
        #pragma unroll
        for (int o = 0; o < N_OUTPUTS; ++o) {
            float2 r0 = red[(0 * N_OUTPUTS + o) * 64 + t];
            float2 r1 = red[(1 * N_OUTPUTS + o) * 64 + t];
            float2 r2 = red[(2 * N_OUTPUTS + o) * 64 + t];
            float2 r3 = red[(3 * N_OUTPUTS + o) * 64 + t];
            s[o].x = ((r0.x + r1.x) + (r2.x + r3.x)) * sc[o];
            s[o].y = ((r0.y + r1.y) + (r2.y + r3.y)) * sc[o];
        }
        float4* outv = (float4*)(out + (s0 + 2 * t) * N_OUTPUTS);
        outv[0] = make_float4(s[0].x, s[1].x, s[2].x, s[3].x);
        outv[1] = make_float4(s[4].x, s[5].x, s[6].x, s[7].x);
        outv[2] = make_float4(s[0].y, s[1].y, s[2].y, s[3].y);
        outv[3] = make_float4(s[4].y, s[5].y, s[6].y, s[7].y);
    }
}

extern "C" void kernel_launch(void* const* d_in, const int* in_sizes, int n_in,
                              void* d_out, int out_size, void* d_ws, size_t ws_size,
                              hipStream_t stream_)
{
    const float* X     = (const float*)d_in[0];  // [524288][64]
    const float* gw    = (const float*)d_in[1];  // [64][130]
    const float* ow    = (const float*)d_in[2];  // [64][8]
    const float* scale = (const float*)d_in[3];  // [8]
    float* out = (float*)d_out;                  // [524288][8]

    int* stream_ws = (int*)d_ws;                 // NWAVES*MAXW*4 = 3072 B

    plan_kernel<<<1, 256, 0, stream_>>>(gw, stream_ws);

    const int blocks = N_SAMPLES / 128;          // 4096
    circuit_kernel<<<blocks, 256, 0, stream_>>>(X, stream_ws, ow, scale, out);
}

// Round 5
// 230.469 us; speedup vs baseline: 2.4583x; 1.0110x over previous
//
#include <hip/hip_runtime.h>
#include <hip/hip_fp16.h>

// Problem constants (from reference)
#define N_SAMPLES 524288
#define N_FEATURES 64
#define N_GATES 64
#define N_OUTPUTS 8
#define BASE_COLS 66          // N_FEATURES + 2 (zero col, one col)
#define MAX_CONN 130          // BASE + N_GATES

#define NWAVES 8              // waves per circuit block (512 threads)
#define MAXW 256              // stream ints per wave (worst case 193)
#define ROWS 131              // 0-63 feat, 64 c0, 65 c1, 66-129 gates, 130 dummy
#define GWS_STR 131           // plan LDS stride for gate weights
#define PAD_SLOT (64 | (64 << 8) | (130 << 16))   // const0*const0 -> dummy row

typedef float v2f __attribute__((ext_vector_type(2)));

// ---------------------------------------------------------------------------
// top-2 insert, tie-break lower index (matches jax.lax.top_k stable order)
// ---------------------------------------------------------------------------
__device__ __forceinline__ void top2_ins(float x, int j, float& v1, int& i1, float& v2, int& i2) {
    bool gt1 = (x > v1) || (x == v1 && j < i1);
    bool gt2 = (x > v2) || (x == v2 && j < i2);
    if (gt1) { v2 = v1; i2 = i1; v1 = x; i1 = j; }
    else if (gt2) { v2 = x; i2 = j; }
}

// ---------------------------------------------------------------------------
// Kernel 1: plan (256 threads). Top-2 per gate (strip-parallel), dataflow
// levels (shfl relaxation), then 8 per-wave instruction streams:
//   slot int = rowA | rowB<<8 | wrRow<<16 | gateId<<24   (>= 0)
//   -1 = level barrier, -2 = end.
// Each level's gates are split round-robin over 8 waves; per-wave lists are
// padded to a MULTIPLE OF 2 (paired-slot batching in the circuit kernel) and
// identical barrier structure across waves.
// ---------------------------------------------------------------------------
__global__ __launch_bounds__(256) void plan_kernel(
    const float* __restrict__ gw,
    int* __restrict__ stream)             // [NWAVES][MAXW]
{
    __shared__ float gws[N_GATES * GWS_STR];            // 33,536 B
    __shared__ float pv1[4][N_GATES], pv2[4][N_GATES];  // 2 KB
    __shared__ int   pi1[4][N_GATES], pi2[4][N_GATES];  // 2 KB
    __shared__ int   streamL[NWAVES * MAXW];            // 8 KB

    const int tid = threadIdx.x;

    // ---- stage 64x130 gate weights, vectorized + coalesced
    const float4* gw4 = (const float4*)gw;              // 2080 float4s
    for (int k = tid; k < (N_GATES * MAX_CONN) / 4; k += 256) {
        float4 v = gw4[k];
        int base = 4 * k;
        #pragma unroll
        for (int e = 0; e < 4; ++e) {
            int idx = base + e;
            int gi  = idx / MAX_CONN;
            int jj  = idx - gi * MAX_CONN;
            gws[gi * GWS_STR + jj] = (&v.x)[e];
        }
    }
    __syncthreads();

    // ---- partial top-2: thread (gate g, strip s), ~33 columns each
    {
        const int g = tid & 63, s = tid >> 6;
        const int avail = BASE_COLS + g;
        int j0 = s * 33;
        int j1 = j0 + 33; if (j1 > avail) j1 = avail;
        float v1 = -1e30f, v2 = -1e30f;
        int   i1 = 0x7fffffff, i2 = 0x7fffffff;
        const float* w = gws + g * GWS_STR;
        for (int j = j0; j < j1; ++j)
            top2_ins(w[j], j, v1, i1, v2, i2);
        pv1[s][g] = v1; pi1[s][g] = i1;
        pv2[s][g] = v2; pi2[s][g] = i2;
    }
    __syncthreads();

    if (tid >= 64) return;              // wave 0 finishes alone (no barriers below)
    const int l = tid;                  // lane == gate id

    // ---- merge strip partials
    float v1 = -1e30f, v2 = -1e30f;
    int   i1 = 0x7fffffff, i2 = 0x7fffffff;
    #pragma unroll
    for (int s = 0; s < 4; ++s) {
        top2_ins(pv1[s][l], pi1[s][l], v1, i1, v2, i2);
        top2_ins(pv2[s][l], pi2[s][l], v1, i1, v2, i2);
    }

    // ---- dataflow level: parallel relaxation (preds have smaller gate id)
    const bool ga = (i1 >= BASE_COLS), gb = (i2 >= BASE_COLS);
    const int  pa = ga ? (i1 - BASE_COLS) : 0;
    const int  pb = gb ? (i2 - BASE_COLS) : 0;
    int lvl = 0;
    bool changed = true;
    while (__any(changed)) {
        int la = __shfl(lvl, pa);
        int lb = __shfl(lvl, pb);
        int nl = lvl;
        if (ga && la + 1 > nl) nl = la + 1;
        if (gb && lb + 1 > nl) nl = lb + 1;
        changed = (nl != lvl);
        lvl = nl;
    }

    // ---- default-fill streams with END (-2); later same-wave DS overwrites are in-order
    for (int q = l; q < NWAVES * MAXW; q += 64) streamL[q] = -2;

    // ---- per-level: pads (to multiple of 2) + barrier sentinel, record own position
    int p_base = 0, assigned = 0;
    int myW = 0, myP = 0;
    for (int L = 0; L < 64 && assigned < 64; ++L) {
        unsigned long long mask = __ballot(lvl == L);
        int c = __popcll(mask);
        if (!c) continue;
        int m  = (c + NWAVES - 1) >> 3;          // real steps per wave this level
        int mp = (m + 1) & ~1;                   // padded to multiple of 2 (<= 8)
        if (lvl == L) {
            int r = __popcll(mask & ((1ull << l) - 1ull));
            myW = r & 7; myP = p_base + (r >> 3);
        }
        if (l <= mp) {
            int val = (l == mp) ? -1 : PAD_SLOT;
            #pragma unroll
            for (int wv = 0; wv < NWAVES; ++wv)
                streamL[wv * MAXW + p_base + l] = val;
        }
        p_base += mp + 1;
        assigned += c;
    }

    // ---- scatter real slots (overwrite pads; same-wave DS is in-order)
    streamL[myW * MAXW + myP] = i1 | (i2 << 8) | ((BASE_COLS + l) << 16) | (l << 24);

    // ---- copy out
    for (int q = l; q < NWAVES * MAXW; q += 64) stream[q] = streamL[q];
}

// ---------------------------------------------------------------------------
// Kernel 2: circuit. 512 threads = 8 waves SHARING one 131-row LDS buffer for
// the same 128 samples (33.5 KB). LDS permits 4 blocks/CU; __launch_bounds__
// (512,6) targets VGPR<=84 -> 3 blocks/CU = 24 waves/CU (6/SIMD).
// Waves execute private streams (4 VGPRs, fetched via v_readlane, uniform p);
// slots processed in PAIRS: 4 ds_reads issued, one wait, 2 hfma2 + 2 writes.
// Rows swizzled r*64 + (w ^ (r&31)) -> all accesses conflict-free.
// Inline per-wave GEMV; flat 3-level cross-wave LDS reduction tree.
// ---------------------------------------------------------------------------
__global__ __launch_bounds__(512, 6) void circuit_kernel(
    const float* __restrict__ X,
    const int*   __restrict__ stream,   // [NWAVES][MAXW]
    const float* __restrict__ ow,       // [N_GATES][N_OUTPUTS]
    const float* __restrict__ scale,    // [N_OUTPUTS]
    float*       __restrict__ out)      // [N_SAMPLES][N_OUTPUTS]
{
    __shared__ __align__(16) __half2 buf[ROWS * 64];  // 33,536 B

    const int tid = threadIdx.x;
    const int w = tid >> 6, t = tid & 63;
    const long long s0 = (long long)blockIdx.x * 128;

    // ---- preload this wave's stream into 4 VGPRs (covers MAXW=256)
    const int* st = stream + w * MAXW;
    const int sv0 = st[t], sv1 = st[64 + t], sv2 = st[128 + t], sv3 = st[192 + t];

    // ---- stage X chunk (128 samples x 64 feats) -> swizzled fp16x2 rows.
    // 1024 tasks: q = k*512+tid, c4 = q&15 (float4 col), j = q>>4 (word).
    const float4* Xv = (const float4*)(X + s0 * N_FEATURES);
    #pragma unroll
    for (int k = 0; k < 2; ++k) {
        int q  = k * 512 + tid;
        int c4 = q & 15;
        int j  = q >> 4;
        float4 va = Xv[(2 * j)     * 16 + c4];
        float4 vb = Xv[(2 * j + 1) * 16 + c4];
        int c = 4 * c4;
        buf[(c + 0) * 64 + (j ^ ((c + 0) & 31))] = __halves2half2(__float2half(va.x), __float2half(vb.x));
        buf[(c + 1) * 64 + (j ^ ((c + 1) & 31))] = __halves2half2(__float2half(va.y), __float2half(vb.y));
        buf[(c + 2) * 64 + (j ^ ((c + 2) & 31))] = __halves2half2(__float2half(va.z), __float2half(vb.z));
        buf[(c + 3) * 64 + (j ^ ((c + 3) & 31))] = __halves2half2(__float2half(va.w), __float2half(vb.w));
    }
    if (tid < 64)        buf[64 * 64 + tid]              = __half2half2(__float2half(0.0f)); // row 64 (xor 0)
    else if (tid < 128)  buf[65 * 64 + ((tid - 64) ^ 1)] = __half2half2(__float2half(1.0f)); // row 65 (xor 1)
    __syncthreads();

    const __half2 one2 = __half2half2(__float2half(1.0f));
    v2f acc[N_OUTPUTS];
    #pragma unroll
    for (int o = 0; o < N_OUTPUTS; ++o) { acc[o].x = 0.0f; acc[o].y = 0.0f; }

    #define FETCH(P) ((P) < 128 \
        ? ((P) < 64  ? __builtin_amdgcn_readlane(sv0, (P))       : __builtin_amdgcn_readlane(sv1, (P) - 64)) \
        : ((P) < 192 ? __builtin_amdgcn_readlane(sv2, (P) - 128) : __builtin_amdgcn_readlane(sv3, (P) - 192)))

    // ---- stream interpreter: paired slots + level barriers
    int p = 0;
    while (true) {
        int sa = FETCH(p);
        if (sa < 0) {
            ++p;
            if (sa == -1) { __syncthreads(); continue; }   // level boundary
            break;                                          // -2: end
        }
        int sb = FETCH(p + 1);                              // pair guaranteed by plan
        p += 2;

        const int ra0 =  sa        & 255, rb0 = (sa >> 8) & 255;
        const int wr0 = (sa >> 16) & 255, g0  = (sa >> 24) & 63;
        const int ra1 =  sb        & 255, rb1 = (sb >> 8) & 255;
        const int wr1 = (sb >> 16) & 255, g1  = (sb >> 24) & 63;

        // 4 independent reads -> single wait
        __half2 a0 = buf[ra0 * 64 + (t ^ (ra0 & 31))];
        __half2 b0 = buf[rb0 * 64 + (t ^ (rb0 & 31))];
        __half2 a1 = buf[ra1 * 64 + (t ^ (ra1 & 31))];
        __half2 b1 = buf[rb1 * 64 + (t ^ (rb1 & 31))];

        __half2 v0 = __hfma2(__hneg2(a0), b0, one2);        // 1 - a*b (2 samples)
        __half2 v1 = __hfma2(__hneg2(a1), b1, one2);
        buf[wr0 * 64 + (t ^ (wr0 & 31))] = v0;
        buf[wr1 * 64 + (t ^ (wr1 & 31))] = v1;

        if (wr0 != 130) {
            v2f g2; g2.x = __low2float(v0); g2.y = __high2float(v0);
            #pragma unroll
            for (int o = 0; o < N_OUTPUTS; ++o) {
                float wt = ow[g0 * N_OUTPUTS + o];           // uniform -> s_load
                v2f wv; wv.x = wt; wv.y = wt;
                acc[o] = __builtin_elementwise_fma(g2, wv, acc[o]);
            }
        }
        if (wr1 != 130) {
            v2f g2; g2.x = __low2float(v1); g2.y = __high2float(v1);
            #pragma unroll
            for (int o = 0; o < N_OUTPUTS; ++o) {
                float wt = ow[g1 * N_OUTPUTS + o];
                v2f wv; wv.x = wt; wv.y = wt;
                acc[o] = __builtin_elementwise_fma(g2, wv, acc[o]);
            }
        }
    }
    #undef FETCH

    // ---- cross-wave reduction: flat tree in dead buffer (32 KB reuse)
    // idx(w,o,t) = w*512 + o*64 + t  (float2 per entry)
    __syncthreads();
    float2* red = (float2*)buf;
    #pragma unroll
    for (int o = 0; o < N_OUTPUTS; ++o) {
        float2 v; v.x = acc[o].x; v.y = acc[o].y;
        red[w * 512 + o * 64 + t] = v;
    }
    __syncthreads();
    #pragma unroll
    for (int k = 0; k < 4; ++k) {                 // waves 0-3 += waves 4-7
        int f = k * 512 + tid;
        float2 a = red[f], b = red[f + 2048];
        a.x += b.x; a.y += b.y; red[f] = a;
    }
    __syncthreads();
    #pragma unroll
    for (int k = 0; k < 2; ++k) {                 // waves 0-1 += waves 2-3
        int f = k * 512 + tid;
        float2 a = red[f], b = red[f + 1024];
        a.x += b.x; a.y += b.y; red[f] = a;
    }
    __syncthreads();
    {                                             // wave 0 += wave 1
        int f = tid;
        float2 a = red[f], b = red[f + 512];
        a.x += b.x; a.y += b.y; red[f] = a;
    }
    __syncthreads();

    if (w == 0) {
        float sc[N_OUTPUTS];
        #pragma unroll
        for (int o = 0; o < N_OUTPUTS; ++o) sc[o] = scale[o];

        float2 s[N_OUTPUTS];
        #pragma unroll
        for (int o = 0; o < N_OUTPUTS; ++o) {
            float2 r = red[o * 64 + t];
            s[o].x = r.x * sc[o]; s[o].y = r.y * sc[o];
        }
        float4* outv = (float4*)(out + (s0 + 2 * t) * N_OUTPUTS);
        outv[0] = make_float4(s[0].x, s[1].x, s[2].x, s[3].x);
        outv[1] = make_float4(s[4].x, s[5].x, s[6].x, s[7].x);
        outv[2] = make_float4(s[0].y, s[1].y, s[2].y, s[3].y);
        outv[3] = make_float4(s[4].y, s[5].y, s[6].y, s[7].y);
    }
}

extern "C" void kernel_launch(void* const* d_in, const int* in_sizes, int n_in,
                              void* d_out, int out_size, void* d_ws, size_t ws_size,
                              hipStream_t stream_)
{
    const float* X     = (const float*)d_in[0];  // [524288][64]
    const float* gw    = (const float*)d_in[1];  // [64][130]
    const float* ow    = (const float*)d_in[2];  // [64][8]
    const float* scale = (const float*)d_in[3];  // [8]
    float* out = (float*)d_out;                  // [524288][8]

    int* stream_ws = (int*)d_ws;                 // NWAVES*MAXW*4 = 8192 B

    plan_kernel<<<1, 256, 0, stream_>>>(gw, stream_ws);

    const int blocks = N_SAMPLES / 128;          // 4096
    circuit_kernel<<<blocks, 512, 0, stream_>>>(X, stream_ws, ow, scale, out);
}